// Round 2
// baseline (99.724 us; speedup 1.0000x reference)
//
#include <hip/hip_runtime.h>
#include <math.h>

#define BATCH 131072
#define EPS 1e-8f

// ws layout (floats):
// [0..255]     logw (16x16, [j][0]=0)
// [256]        alpha = logdet(L0 + I)
// [1024..66559] T table: logdet(L0[S,S]) for all 65536 masks

// Per-thread fully-unrolled LU (no pivoting — valid: sym part of L0 is PD,
// so all principal minors > 0 and pivots stay positive).
// Column-only masking: column j = e_j when mask bit j is 0. Pad columns stay
// e_j through elimination (a[k'][j]==0 for k'!=j), so pad pivots == 1 and
// active pivots equal those of LU(L0[S,S]).
__device__ __forceinline__ float lu_logdet(const float* sL0, unsigned m,
                                           float diagAdd) {
    float a[16][16];
    #pragma unroll
    for (int j = 0; j < 16; ++j) {
        bool on = (m >> j) & 1u;
        #pragma unroll
        for (int i = 0; i < 16; ++i) {
            float v = on ? sL0[i * 16 + j] : 0.f;
            if (i == j) v = on ? (v + diagAdd) : 1.f;
            a[i][j] = v;
        }
    }
    float logdet = 0.f;
    #pragma unroll
    for (int k = 0; k < 16; ++k) {
        float piv = a[k][k];
        logdet += __logf(fabsf(piv));
        float inv = 1.0f / piv;
        #pragma unroll
        for (int i2 = k + 1; i2 < 16; ++i2) {
            float f = a[i2][k] * inv;
            #pragma unroll
            for (int j2 = k + 1; j2 < 16; ++j2)
                a[i2][j2] = fmaf(-f, a[k][j2], a[i2][j2]);
        }
    }
    return logdet;
}

// Blocks 0..1023: 64 masks each (tid 0..65535) -> T table.
// Block 1024: lane 0 -> alpha; lanes 32..47 -> logw rows.
__global__ __launch_bounds__(64, 1) void table_kernel(
    const float* __restrict__ W, const float* __restrict__ A,
    const float* __restrict__ Bm, const float* __restrict__ Cm,
    float* __restrict__ ws) {
    __shared__ float sL0[256];
    int lt = threadIdx.x;

    // Cooperative L0 build: each thread computes 4 entries.
    #pragma unroll
    for (int q = 0; q < 4; ++q) {
        int e = lt * 4 + q;
        int i = e >> 4, j = e & 15;
        float s = 0.f;
        #pragma unroll
        for (int k = 0; k < 16; ++k) {
            s += A[k * 16 + i] * A[k * 16 + j];    // (A^T A)[i][j]
            s += Bm[i * 16 + k] * Cm[j * 16 + k]   // (B C^T)[i][j]
               - Cm[i * 16 + k] * Bm[j * 16 + k];  // (C B^T)[i][j]
        }
        if (i == j) s += EPS;
        sL0[e] = s;
    }
    __syncthreads();

    unsigned blk = blockIdx.x;
    if (blk < 1024u) {
        unsigned m = blk * 64u + (unsigned)lt;
        ws[1024 + m] = lu_logdet(sL0, m, 0.f);
    } else {
        if (lt == 0) {
            ws[256] = lu_logdet(sL0, 0xFFFFu, 1.f);   // alpha = logdet(L0+I)
        } else if (lt >= 32 && lt < 48) {
            int r = lt - 32;                           // log-softmax row r
            float row[15];
            float mx = -1e30f;
            #pragma unroll
            for (int q = 0; q < 15; ++q) {
                row[q] = W[r * 15 + q];
                mx = fmaxf(mx, row[q]);
            }
            float se = 0.f;
            #pragma unroll
            for (int q = 0; q < 15; ++q) se += expf(row[q] - mx);
            float lse = mx + logf(se);
            ws[r * 16 + 0] = 0.f;
            #pragma unroll
            for (int q = 0; q < 15; ++q) ws[r * 16 + 1 + q] = row[q] - lse;
        }
    }
}

__global__ __launch_bounds__(256) void main_kernel(const int4* __restrict__ x,
                                                   const float* __restrict__ ws,
                                                   float* __restrict__ out) {
    __shared__ float slw[256];
    int lt = threadIdx.x;
    slw[lt] = ws[lt];
    __syncthreads();

    int b = blockIdx.x * 256 + lt;
    const int4* xb = x + (size_t)b * 16;

    float lw = 0.f;
    unsigned mask = 0;
    #pragma unroll
    for (int j = 0; j < 16; ++j) {
        int4 v = xb[j];                              // 4 bits of part j
        int idx = v.x + 2 * v.y + 4 * v.z + 8 * v.w; // 0..15
        lw += slw[j * 16 + idx];                     // logw[j][0]==0
        mask |= (idx != 0 ? 1u : 0u) << j;
    }
    out[b] = lw + ws[1024 + mask] - ws[256];
}

extern "C" void kernel_launch(void* const* d_in, const int* in_sizes, int n_in,
                              void* d_out, int out_size, void* d_ws, size_t ws_size,
                              hipStream_t stream) {
    const int4*  x = (const int4*)d_in[0];
    const float* W = (const float*)d_in[1];
    const float* A = (const float*)d_in[2];
    const float* B = (const float*)d_in[3];
    const float* C = (const float*)d_in[4];
    float* ws  = (float*)d_ws;
    float* out = (float*)d_out;

    table_kernel<<<1025, 64, 0, stream>>>(W, A, B, C, ws);
    main_kernel<<<BATCH / 256, 256, 0, stream>>>(x, ws, out);
}